// Round 11
// baseline (371.442 us; speedup 1.0000x reference)
//
#include <hip/hip_runtime.h>
#include <hip/hip_bf16.h>
#include <cstdint>
#include <cmath>

// Problem constants
#define B_   2
#define S_   2048
#define H_   2048
#define NH_  32
#define NKV_ 8
#define HD_  64
#define CSTR 3072   // row stride of the concatenated QKV output [4096, 3072]

using bf16x8 = __attribute__((ext_vector_type(8))) short;
using f32x4  = __attribute__((ext_vector_type(4))) float;

#define MFMA16(a, b, c) __builtin_amdgcn_mfma_f32_16x16x32_bf16((a), (b), (c), 0, 0, 0)

__device__ __forceinline__ short f2bf(float f) {   // round-nearest-even
  uint32_t u = __float_as_uint(f);
  uint32_t r = (u + 0x7fffu + ((u >> 16) & 1u)) >> 16;
  return (short)r;
}
__device__ __forceinline__ float bf2f(short s) {
  return __uint_as_float(((uint32_t)(uint16_t)s) << 16);
}
// packed 2xf32 -> 2xbf16 (hardware op when available)
__device__ __forceinline__ uint32_t f2bf_pk(float a, float b) {
#if __has_builtin(__builtin_amdgcn_cvt_pk_bf16_f32)
  auto r = __builtin_amdgcn_cvt_pk_bf16_f32(a, b);
  uint32_t u; __builtin_memcpy(&u, &r, sizeof(u));
  return u;
#else
  uint32_t ua = (__float_as_uint(a) + 0x8000u) >> 16;
  uint32_t ub = (__float_as_uint(b) + 0x8000u) >> 16;
  return ua | (ub << 16);
#endif
}
// raw v_exp_f32 (2^x)
__device__ __forceinline__ float fast_exp2(float x) {
#if __has_builtin(__builtin_amdgcn_exp2f)
  return __builtin_amdgcn_exp2f(x);
#else
  return exp2f(x);
#endif
}

__device__ __forceinline__ void gload_lds16(const void* g, void* l) {
  __builtin_amdgcn_global_load_lds((const __attribute__((address_space(1))) void*)g,
                                   (__attribute__((address_space(3))) void*)l, 16, 0, 0);
}

// ---------------- fused fp32 -> bf16 convert for all 5 tensors ------------------
struct Cvt5Args {
  const float *s0, *s1, *s2, *s3, *s4;
  short *d0, *d1, *d2, *d3, *d4;
};
#define CV0 2097152             // hs      (float4 units)
#define CV1 (CV0 + 1048576)     // Wq
#define CV2 (CV1 + 262144)      // Wk
#define CV3 (CV2 + 262144)      // Wv
#define CV4 (CV3 + 1048576)     // Wo -> total 4718592
__global__ void cvt5_kernel(Cvt5Args a) {
  int i = blockIdx.x * blockDim.x + threadIdx.x;
  const float* s; short* d; int off;
  if      (i < CV0) { s = a.s0; d = a.d0; off = i; }
  else if (i < CV1) { s = a.s1; d = a.d1; off = i - CV0; }
  else if (i < CV2) { s = a.s2; d = a.d2; off = i - CV1; }
  else if (i < CV3) { s = a.s3; d = a.d3; off = i - CV2; }
  else              { s = a.s4; d = a.d4; off = i - CV3; }
  const float4 v = ((const float4*)s)[off];
  uint2 o;
  o.x = (uint32_t)(uint16_t)f2bf(v.x) | ((uint32_t)(uint16_t)f2bf(v.y) << 16);
  o.y = (uint32_t)(uint16_t)f2bf(v.z) | ((uint32_t)(uint16_t)f2bf(v.w) << 16);
  ((uint2*)d)[off] = o;
}

// ---------------- 128x192 QKV-cat GEMM: grid 16x32 = 512 blocks = 2/CU ---------
// Ccat[4096,3072] = X[4096,2048] * Wcat[3072,2048]^T. BK=64, 512 threads =
// 8 waves (2M x 4N); per wave 64x48 output = 4x3 16x16 frags (48 acc VGPR).
// LDS = A 2x16K + B 2x24K = EXACTLY 80 KiB -> 2 blocks/CU (4 waves/SIMD).
// R7-verified: 52 us, MfmaUtil ~41, 990 TF. Cross-block overlap (m114) covers
// the end-of-tile vmcnt(0) drain. Protocol & XOR swizzle unchanged.
__global__ __launch_bounds__(512, 4) void gemm_qkvcat(
    const short* __restrict__ A, const short* __restrict__ Bcat,
    short* __restrict__ Ccat)
{
  __shared__ __align__(16) short As[2][128 * 64];   // 32 KiB
  __shared__ __align__(16) short Bs[2][192 * 64];   // 48 KiB

  const long tileM = (long)blockIdx.y * 128;
  const long tileN = (long)blockIdx.x * 192;
  const int  K = 2048;

  const int tid  = threadIdx.x;
  const int lane = tid & 63;
  const int quad = lane >> 4;
  const int l15  = lane & 15;
  const int wave = tid >> 6;
  const int wm   = (wave >> 2) * 64;      // 0 / 64
  const int wn   = (wave & 3) * 48;       // 0..144 (multiple of 16)
  const int xsw  = l15 & 7;

  f32x4 acc[4][3];
#pragma unroll
  for (int i = 0; i < 4; ++i)
#pragma unroll
    for (int j = 0; j < 3; ++j) acc[i][j] = f32x4{0.f, 0.f, 0.f, 0.f};

  // Staging: thread c = tid + 512p covers row c>>3, LDS chunk c&7 (linear dest).
  // Global source chunk = swizzle inverse. A: 2 passes (128 rows), B: 3 (192).
  const int cS = (tid & 7) ^ ((tid >> 3) & 7);
  const short* gA[2]; const short* gB[3];
#pragma unroll
  for (int p = 0; p < 2; ++p)
    gA[p] = A + (tileM + (tid >> 3) + 64 * p) * K + cS * 8;
#pragma unroll
  for (int p = 0; p < 3; ++p)
    gB[p] = Bcat + (tileN + (tid >> 3) + 64 * p) * K + cS * 8;

  auto stage = [&](int buf, int t) {
    const long ko = (long)t * 64;
    short* la = &As[buf][0];
    short* lb = &Bs[buf][0];
#pragma unroll
    for (int p = 0; p < 2; ++p)
      gload_lds16(gA[p] + ko, la + (tid + p * 512) * 8);
#pragma unroll
    for (int p = 0; p < 3; ++p)
      gload_lds16(gB[p] + ko, lb + (tid + p * 512) * 8);
  };

  const int NT = K / 64;                       // 32
  stage(0, 0);
  asm volatile("s_waitcnt vmcnt(0)" ::: "memory");
  asm volatile("s_barrier" ::: "memory");

  bf16x8 af[2][2], bfr[3][2];

  auto ldA = [&](const short* Ab, int half) {
#pragma unroll
    for (int m = 0; m < 2; ++m) {
      const int r = wm + (half * 2 + m) * 16 + l15;
#pragma unroll
      for (int kk = 0; kk < 2; ++kk)
        af[m][kk] = *(const bf16x8*)&Ab[r * 64 + (((kk * 4 + quad) ^ xsw) << 3)];
    }
  };
  auto ldB = [&](const short* Bb) {
#pragma unroll
    for (int n = 0; n < 3; ++n) {
      const int r = wn + n * 16 + l15;
#pragma unroll
      for (int kk = 0; kk < 2; ++kk)
        bfr[n][kk] = *(const bf16x8*)&Bb[r * 64 + (((kk * 4 + quad) ^ xsw) << 3)];
    }
  };
  auto mma = [&](int half) {
    __builtin_amdgcn_s_setprio(1);
#pragma unroll
    for (int m = 0; m < 2; ++m)
#pragma unroll
      for (int n = 0; n < 3; ++n)
#pragma unroll
        for (int kk = 0; kk < 2; ++kk)
          acc[half * 2 + m][n] = MFMA16(af[m][kk], bfr[n][kk], acc[half * 2 + m][n]);
    __builtin_amdgcn_s_setprio(0);
  };

  for (int t = 0; t < NT; ++t) {
    const int cur = t & 1;
    const short* Ab = &As[cur][0];
    const short* Bb = &Bs[cur][0];

    // phase 0: stage next tile, mf-half 0 (B loaded once, reused in half 1)
    if (t + 1 < NT) stage(cur ^ 1, t + 1);
    ldB(Bb); ldA(Ab, 0); mma(0);
    asm volatile("s_barrier" ::: "memory");
    // phase 1: mf-half 1
    ldA(Ab, 1); mma(1);
    asm volatile("s_waitcnt vmcnt(0)" ::: "memory");    // next-tile DMA landed
    asm volatile("s_waitcnt lgkmcnt(0)" ::: "memory");  // my reads of slot cur done
    asm volatile("s_barrier" ::: "memory");             // release slot cur
  }

#pragma unroll
  for (int i = 0; i < 4; ++i)
#pragma unroll
    for (int j = 0; j < 3; ++j)
#pragma unroll
      for (int r = 0; r < 4; ++r) {
        long row = tileM + wm + i * 16 + quad * 4 + r;
        long col = tileN + wn + j * 16 + l15;
        Ccat[row * CSTR + col] = f2bf(acc[i][j][r]);
      }
}

// ---------------- 128x128 GEMM (output projection): 512 blocks = 2/CU ----------
// Cf[4096,2048] = A[4096,2048] * Wo[2048,2048]^T, fp32 epilogue. Same protocol.
// Per wave 64x32 = 4x2 frags (32 acc VGPR). LDS 64 KiB -> 2 blocks/CU.
__global__ __launch_bounds__(512, 4) void gemm_out(
    const short* __restrict__ A, const short* __restrict__ Bm,
    float* __restrict__ Cf)
{
  __shared__ __align__(16) short As[2][128 * 64];   // 32 KiB
  __shared__ __align__(16) short Bs[2][128 * 64];   // 32 KiB

  const int N = 2048, K = 2048;
  const long tileM = (long)blockIdx.y * 128;
  const long tileN = (long)blockIdx.x * 128;

  const int tid  = threadIdx.x;
  const int lane = tid & 63;
  const int quad = lane >> 4;
  const int l15  = lane & 15;
  const int wave = tid >> 6;
  const int wm   = (wave >> 2) * 64;
  const int wn   = (wave & 3) * 32;
  const int xsw  = l15 & 7;

  f32x4 acc[4][2];
#pragma unroll
  for (int i = 0; i < 4; ++i)
#pragma unroll
    for (int j = 0; j < 2; ++j) acc[i][j] = f32x4{0.f, 0.f, 0.f, 0.f};

  const int cS = (tid & 7) ^ ((tid >> 3) & 7);
  const short* gA[2]; const short* gB[2];
#pragma unroll
  for (int p = 0; p < 2; ++p) {
    gA[p] = A  + (tileM + (tid >> 3) + 64 * p) * K + cS * 8;
    gB[p] = Bm + (tileN + (tid >> 3) + 64 * p) * K + cS * 8;
  }

  auto stage = [&](int buf, int t) {
    const long ko = (long)t * 64;
    short* la = &As[buf][0];
    short* lb = &Bs[buf][0];
#pragma unroll
    for (int p = 0; p < 2; ++p) {
      gload_lds16(gA[p] + ko, la + (tid + p * 512) * 8);
      gload_lds16(gB[p] + ko, lb + (tid + p * 512) * 8);
    }
  };

  const int NT = K / 64;
  stage(0, 0);
  asm volatile("s_waitcnt vmcnt(0)" ::: "memory");
  asm volatile("s_barrier" ::: "memory");

  bf16x8 af[2][2], bfr[2][2];

  auto ldA = [&](const short* Ab, int half) {
#pragma unroll
    for (int m = 0; m < 2; ++m) {
      const int r = wm + (half * 2 + m) * 16 + l15;
#pragma unroll
      for (int kk = 0; kk < 2; ++kk)
        af[m][kk] = *(const bf16x8*)&Ab[r * 64 + (((kk * 4 + quad) ^ xsw) << 3)];
    }
  };
  auto ldB = [&](const short* Bb) {
#pragma unroll
    for (int n = 0; n < 2; ++n) {
      const int r = wn + n * 16 + l15;
#pragma unroll
      for (int kk = 0; kk < 2; ++kk)
        bfr[n][kk] = *(const bf16x8*)&Bb[r * 64 + (((kk * 4 + quad) ^ xsw) << 3)];
    }
  };
  auto mma = [&](int half) {
    __builtin_amdgcn_s_setprio(1);
#pragma unroll
    for (int m = 0; m < 2; ++m)
#pragma unroll
      for (int n = 0; n < 2; ++n)
#pragma unroll
        for (int kk = 0; kk < 2; ++kk)
          acc[half * 2 + m][n] = MFMA16(af[m][kk], bfr[n][kk], acc[half * 2 + m][n]);
    __builtin_amdgcn_s_setprio(0);
  };

  for (int t = 0; t < NT; ++t) {
    const int cur = t & 1;
    const short* Ab = &As[cur][0];
    const short* Bb = &Bs[cur][0];

    if (t + 1 < NT) stage(cur ^ 1, t + 1);
    ldB(Bb); ldA(Ab, 0); mma(0);
    asm volatile("s_barrier" ::: "memory");
    ldA(Ab, 1); mma(1);
    asm volatile("s_waitcnt vmcnt(0)" ::: "memory");
    asm volatile("s_waitcnt lgkmcnt(0)" ::: "memory");
    asm volatile("s_barrier" ::: "memory");
  }

#pragma unroll
  for (int i = 0; i < 4; ++i)
#pragma unroll
    for (int j = 0; j < 2; ++j)
#pragma unroll
      for (int r = 0; r < 4; ++r) {
        long row = tileM + wm + i * 16 + quad * 4 + r;
        long col = tileN + wn + j * 16 + l15;
        Cf[row * N + col] = acc[i][j][r];
      }
}

// ---------------- fused RoPE (Q,K in-place in Ccat) + V transpose ---------------
// Q = Ccat cols 0..2047, K = cols 2048..2559, V = cols 2560..3071 (stride 3072).
// Vectorized x8; math identical to previous (bit-identical output).
// Q scaled by (1/8)*log2(e); V^T written slot-permuted for the attn PV A-frag.
#define ROPE_BLOCKS 2560          // Q: 2048 blocks, K: 512 blocks (x8 vectorized)
__global__ void rope_vtrans_kernel(short* __restrict__ Ccat, short* __restrict__ Vt) {
  __shared__ short tile[64][65];
  if (blockIdx.x < ROPE_BLOCKS) {
    const int QT = (B_ * S_) * NH_ * 4;  // 524288 Q threads (4 groups of 8 per head)
    int t = blockIdx.x * blockDim.x + threadIdx.x;
    long base; int g; float scale; int row;
    if (t < QT) {
      row = t >> 7; int rem = t & 127, head = rem >> 2; g = rem & 3;
      base = (long)row * CSTR + head * HD_;
      scale = 0.125f * 1.44269504f;
    } else {
      int t2 = t - QT;
      row = t2 >> 5; int rem = t2 & 31, head = rem >> 2; g = rem & 3;
      base = (long)row * CSTR + 2048 + head * HD_;
      scale = 1.0f;
    }
    const int s = row & (S_ - 1);
    const int i0 = g * 8;
    union V8 { bf16x8 v; short e[8]; };
    V8 x0, x1, y0, y1;
    x0.v = *(const bf16x8*)&Ccat[base + i0];
    x1.v = *(const bf16x8*)&Ccat[base + i0 + 32];
#pragma unroll
    for (int j = 0; j < 8; ++j) {
      const int i = i0 + j;
      float invr = exp2f((float)i * -0.41524101f) * 0.15915494309f;
      float rev = (float)s * invr;
      rev -= floorf(rev);
      float ar = rev * 6.28318530718f;
      float c = __cosf(ar), sn = __sinf(ar);
      float a = bf2f(x0.e[j]);
      float b = bf2f(x1.e[j]);
      y0.e[j] = f2bf((a * c - b * sn) * scale);
      y1.e[j] = f2bf((b * c + a * sn) * scale);
    }
    *(bf16x8*)&Ccat[base + i0]      = y0.v;
    *(bf16x8*)&Ccat[base + i0 + 32] = y1.v;
  } else {
    int blk = blockIdx.x - ROPE_BLOCKS;
    int s0 = (blk & 31) * 64;
    int h  = (blk >> 5) & 7;
    int b  = blk >> 8;
    int tid = threadIdx.x;
#pragma unroll
    for (int it = 0; it < 16; ++it) {
      int idx = tid + it * 256;
      int r = idx >> 6, c = idx & 63;
      tile[r][c] = Ccat[((long)(b * S_ + s0 + r)) * CSTR + 2560 + h * HD_ + c];
    }
    __syncthreads();
#pragma unroll
    for (int it = 0; it < 16; ++it) {
      int idx = tid + it * 256;
      int d = idx >> 6, s = idx & 63;
      int slot = (s & 0x20) | (((s >> 2) & 3) << 3) | (((s >> 4) & 1) << 2) | (s & 3);
      Vt[((long)((b * NKV_ + h) * HD_ + d)) * S_ + s0 + slot] = tile[s][d];
    }
  }
}

// ---------------- Flash attention (causal, GQA), transposed-score form ----------
// Grid (16, 64) = 1024 blocks with the R10-verified XCD-aware remap (each
// (b,hkv) K/V column pinned to one XCD; FETCH 33.8 -> 12.4 MB, K/V L2-hot).
// NEW this round: K/V now hits L2 (~200-400cy), so the deep-prefetch insurance
// is no longer worth its LDS. 2 buffers (was 3), 1-deep prefetch, 2-slot
// protocol VERBATIM from the verified gemm_qkvcat: stage(kb+1) at iteration
// top into the other slot, compute kb, vmcnt(0)+lgkmcnt(0)+barrier.
// LDS 48 -> 32 KiB  =>  5 blocks/CU resident (20 waves, 5/SIMD, was 3/12/3) --
// attacks the stall-dominated regime (all pipes <32% busy) with more
// independent wave streams per SIMD; cross-block overlap covers the drain.
// 128 q-rows per block (two 16-row fragments per wave).
__global__ __launch_bounds__(256, 5) void attn_kernel(
    const short* __restrict__ Ccat, const short* __restrict__ Vt,
    short* __restrict__ O)
{
  // ---- XCD-aware index derivation (pure remap of the linear block id) ----
  const int l    = (int)blockIdx.x + 16 * (int)blockIdx.y;  // 0..1023
  const int r8   = l & 7;                 // XCD residue (round-robin)
  const int m    = l >> 3;                // 0..127
  const int kvcol = r8 + 8 * (m >> 6);    // 0..15 = b*8 + hkv (2 per XCD)
  const int idx  = m & 63;                // 0..63 within column
  const int qt   = 15 - (idx & 15);       // long q-tiles dispatch first
  const int kmax = 2 * qt + 1;            // last 64-key tile index
  const int b    = kvcol >> 3;
  const int hkv  = kvcol & 7;
  const int h    = hkv * 4 + (idx >> 4);  // head within the GQA group

  const int tid = threadIdx.x, lane = tid & 63, w = tid >> 6;
  const int quad = lane >> 4, l15 = lane & 15;

  __shared__ __align__(16) short Ks[2][64 * 64];   // [key][feature], chunk-swizzled
  __shared__ __align__(16) short Vs[2][64 * 64];   // [d][slot], chunk-swizzled

  const int qbase = qt * 128 + w * 16;   // frag0 rows qbase+l15, frag1 +64
  const short* qb0 = Ccat + ((long)(b * S_ + qbase + l15)) * CSTR + h * HD_;
  const short* qb1 = qb0 + 64L * CSTR;
  const bf16x8 aq00 = *(const bf16x8*)(qb0 + quad * 8);
  const bf16x8 aq01 = *(const bf16x8*)(qb0 + 32 + quad * 8);
  const bf16x8 aq10 = *(const bf16x8*)(qb1 + quad * 8);
  const bf16x8 aq11 = *(const bf16x8*)(qb1 + 32 + quad * 8);

  f32x4 o0[4], o1[4];
#pragma unroll
  for (int i = 0; i < 4; ++i) {
    o0[i] = f32x4{0.f, 0.f, 0.f, 0.f};
    o1[i] = f32x4{0.f, 0.f, 0.f, 0.f};
  }
  f32x4 li0 = f32x4{0.f, 0.f, 0.f, 0.f};
  f32x4 li1 = f32x4{0.f, 0.f, 0.f, 0.f};

  const short* kg = Ccat + ((long)(b * S_)) * CSTR + 2048 + hkv * HD_;
  const short* vg = Vt + ((long)((b * NKV_ + hkv) * HD_)) * S_;

  const int rK = tid >> 3;                       // 0..31 (second half adds 32)
  const int cC = (tid & 7) ^ (rK & 7);           // +32 preserves &7
  const short* kSrc = kg + (long)rK * CSTR + cC * 8;
  const short* vSrc = vg + (long)rK * S_ + cC * 8;
  short* kDst = &Ks[0][tid * 8];
  short* vDst = &Vs[0][tid * 8];

  auto stage = [&](int buf, int kb) {
    const long ko = (long)kb * 64 * CSTR;
    const long vo = (long)kb * 64;
    const int bo = buf * 4096;
    gload_lds16(kSrc + ko,              kDst + bo);
    gload_lds16(kSrc + ko + 32L * CSTR, kDst + bo + 2048);
    gload_lds16(vSrc + vo,              vDst + bo);
    gload_lds16(vSrc + vo + 32L * S_,   vDst + bo + 2048);
  };

  // prologue: stage tile 0, collective-ready via own-vmcnt + barrier
  stage(0, 0);
  asm volatile("s_waitcnt vmcnt(0)" ::: "memory");
  asm volatile("s_barrier" ::: "memory");

  const int thr = w * 16 + l15;   // diagonal mask threshold (key offset vs row)
  union U8 { uint32_t u[4]; bf16x8 v; };

  int cur = 0;
  for (int kb = 0; kb <= kmax; ++kb) {
    // 1-deep prefetch into the other slot (slot safe: its readers finished at
    // the end-of-previous-iteration lgkmcnt(0)+barrier)
    if (kb < kmax) stage(cur ^ 1, kb + 1);
    const short* Kb = &Ks[cur][0];
    const short* Vb = &Vs[cur][0];
    const bool doF0 = (kb != kmax);              // frag0 fully masked at kmax

    // ---- Sc^T = K·Q^T (K-frags shared across both q-fragments) ----
    f32x4 s0[4], s1[4];
    __builtin_amdgcn_s_setprio(1);
#pragma unroll
    for (int nt = 0; nt < 4; ++nt) {
      const int r = nt * 16 + l15;
      bf16x8 k0 = *(const bf16x8*)&Kb[(r * 8 + ((quad)     ^ (r & 7))) * 8];
      bf16x8 k1 = *(const bf16x8*)&Kb[(r * 8 + ((quad + 4) ^ (r & 7))) * 8];
      f32x4 t = f32x4{0.f, 0.f, 0.f, 0.f};
      t = MFMA16(k0, aq10, t);
      t = MFMA16(k1, aq11, t);
      s1[nt] = t;
      if (doF0) {
        f32x4 u = f32x4{0.f, 0.f, 0.f, 0.f};
        u = MFMA16(k0, aq00, u);
        u = MFMA16(k1, aq01, u);
        s0[nt] = u;
      }
    }
    __builtin_amdgcn_s_setprio(0);

    // ---- causal mask (diagonal tiles only) ----
    if (kb == kmax) {            // frag1 diagonal
#pragma unroll
      for (int nt = 0; nt < 4; ++nt) {
        const int base = nt * 16 + quad * 4;
#pragma unroll
        for (int rr = 0; rr < 4; ++rr)
          if (base + rr > thr) s1[nt][rr] = -1e30f;
      }
    }
    if (doF0 && kb == kmax - 1) {   // frag0 diagonal
#pragma unroll
      for (int nt = 0; nt < 4; ++nt) {
        const int base = nt * 16 + quad * 4;
#pragma unroll
        for (int rr = 0; rr < 4; ++rr)
          if (base + rr > thr) s0[nt][rr] = -1e30f;
      }
    }

    // ---- exp2 + pack to P^T B-fragments (registers only) ----
    U8 p0[2], p1[2];
#pragma unroll
    for (int kt = 0; kt < 2; ++kt) {
      float e0 = fast_exp2(s1[2 * kt][0]),     e1 = fast_exp2(s1[2 * kt][1]);
      float e2 = fast_exp2(s1[2 * kt][2]),     e3 = fast_exp2(s1[2 * kt][3]);
      float e4 = fast_exp2(s1[2 * kt + 1][0]), e5 = fast_exp2(s1[2 * kt + 1][1]);
      float e6 = fast_exp2(s1[2 * kt + 1][2]), e7 = fast_exp2(s1[2 * kt + 1][3]);
      p1[kt].u[0] = f2bf_pk(e0, e1);
      p1[kt].u[1] = f2bf_pk(e2, e3);
      p1[kt].u[2] = f2bf_pk(e4, e5);
      p1[kt].u[3] = f2bf_pk(e6, e7);
      li1 += f32x4{e0, e1, e2, e3};
      li1 += f32x4{e4, e5, e6, e7};
    }
    if (doF0) {
#pragma unroll
      for (int kt = 0; kt < 2; ++kt) {
        float e0 = fast_exp2(s0[2 * kt][0]),     e1 = fast_exp2(s0[2 * kt][1]);
        float e2 = fast_exp2(s0[2 * kt][2]),     e3 = fast_exp2(s0[2 * kt][3]);
        float e4 = fast_exp2(s0[2 * kt + 1][0]), e5 = fast_exp2(s0[2 * kt + 1][1]);
        float e6 = fast_exp2(s0[2 * kt + 1][2]), e7 = fast_exp2(s0[2 * kt + 1][3]);
        p0[kt].u[0] = f2bf_pk(e0, e1);
        p0[kt].u[1] = f2bf_pk(e2, e3);
        p0[kt].u[2] = f2bf_pk(e4, e5);
        p0[kt].u[3] = f2bf_pk(e6, e7);
        li0 += f32x4{e0, e1, e2, e3};
        li0 += f32x4{e4, e5, e6, e7};
      }
    }

    // ---- O^T += V^T · P^T (V A-frags shared across both q-fragments) ----
    __builtin_amdgcn_s_setprio(1);
#pragma unroll
    for (int kt = 0; kt < 2; ++kt) {
      bf16x8 vf[4];
#pragma unroll
      for (int dt = 0; dt < 4; ++dt)
        vf[dt] = *(const bf16x8*)&Vb[(dt * 16 + l15) * 64 +
                                     (((kt * 4 + quad) ^ (l15 & 7)) << 3)];
#pragma unroll
      for (int dt = 0; dt < 4; ++dt)
        o1[dt] = MFMA16(vf[dt], p1[kt].v, o1[dt]);
      if (doF0) {
#pragma unroll
        for (int dt = 0; dt < 4; ++dt)
          o0[dt] = MFMA16(vf[dt], p0[kt].v, o0[dt]);
      }
    }
    __builtin_amdgcn_s_setprio(0);

    // end-of-iteration: next-tile DMA landed (overlapped with the compute
    // above), my LDS reads of slot cur serviced, then collective release.
    asm volatile("s_waitcnt vmcnt(0)" ::: "memory");
    asm volatile("s_waitcnt lgkmcnt(0)" ::: "memory");
    asm volatile("s_barrier" ::: "memory");
    cur ^= 1;
  }

  // ---- epilogue: O^T C-layout -> lane holds qrow=l15, d = dt*16+quad*4+r ----
  auto epi = [&](f32x4 (&o)[4], const f32x4& li4, int qrow0) {
    float l2 = (li4[0] + li4[1]) + (li4[2] + li4[3]);
    l2 += __shfl_xor(l2, 16, 64);
    l2 += __shfl_xor(l2, 32, 64);
    float invl = 1.0f / l2;
    long orow = (long)(b * S_ + qrow0 + l15);
#pragma unroll
    for (int dt = 0; dt < 4; ++dt) {
      uint2 st;
      st.x = f2bf_pk(o[dt][0] * invl, o[dt][1] * invl);
      st.y = f2bf_pk(o[dt][2] * invl, o[dt][3] * invl);
      *(uint2*)&O[orow * (NH_ * HD_) + h * HD_ + dt * 16 + quad * 4] = st;
    }
  };
  epi(o1, li1, qbase + 64);
  epi(o0, li0, qbase);
}

// ---------------- launch -------------------------------------------------------
extern "C" void kernel_launch(void* const* d_in, const int* in_sizes, int n_in,
                              void* d_out, int out_size, void* d_ws, size_t ws_size,
                              hipStream_t stream) {
  const float* hs = (const float*)d_in[0];
  const float* Wq = (const float*)d_in[1];
  const float* Wk = (const float*)d_in[2];
  const float* Wv = (const float*)d_in[3];
  const float* Wo = (const float*)d_in[4];
  float* out = (float*)d_out;

  char* p = (char*)d_ws;
  auto carve = [&](size_t elems) { short* r = (short*)p; p += elems * 2; return r; };
  short* Xb   = carve(8388608);    // hidden bf16 [4096,2048]
  short* Wcat = carve(6291456);    // [Wq;Wk;Wv] rows -> [3072,2048]
  short* Wob  = carve(4194304);
  short* Ccat = carve(12582912);   // QKV-cat [4096,3072]
  short* Vtt  = carve(2097152);    // V^T [B,KV,HD,S] (slot-permuted)
  short* Om   = carve(8388608);    // attn out [4096,2048]

  short* Wqb = Wcat;               // rows 0..2047
  short* Wkb = Wcat + 4194304;     // rows 2048..2559
  short* Wvb = Wcat + 5242880;     // rows 2560..3071

  Cvt5Args ca{hs, Wq, Wk, Wv, Wo, Xb, Wqb, Wkb, Wvb, Wob};
  cvt5_kernel<<<CV4 / 256, 256, 0, stream>>>(ca);

  // QKV-cat projection: 128x192 tiles, grid 16x32 = 512 blocks = 2/CU
  gemm_qkvcat<<<dim3(16, 32), 512, 0, stream>>>(Xb, Wcat, Ccat);

  rope_vtrans_kernel<<<ROPE_BLOCKS + 512, 256, 0, stream>>>(Ccat, Vtt);

  // attention: single launch, grid (16,64) = 1024 blocks, XCD-aware remap,
  // 2-slot LDS (32 KiB) -> 5 blocks/CU resident
  attn_kernel<<<dim3(16, 64, 1), 256, 0, stream>>>(Ccat, Vtt, Om);

  // Output projection: 128x128 tiles, grid 16x32 = 512 blocks = 2/CU
  gemm_out<<<dim3(16, 32), 512, 0, stream>>>(Om, Wob, out);
}

// Round 12
// 278.905 us; speedup vs baseline: 1.3318x; 1.3318x over previous
//
#include <hip/hip_runtime.h>
#include <hip/hip_bf16.h>
#include <cstdint>
#include <cmath>

// Problem constants
#define B_   2
#define S_   2048
#define H_   2048
#define NH_  32
#define NKV_ 8
#define HD_  64
#define CSTR 3072   // row stride of the concatenated QKV output [4096, 3072]

using bf16x8 = __attribute__((ext_vector_type(8))) short;
using f32x4  = __attribute__((ext_vector_type(4))) float;

#define MFMA16(a, b, c) __builtin_amdgcn_mfma_f32_16x16x32_bf16((a), (b), (c), 0, 0, 0)

__device__ __forceinline__ short f2bf(float f) {   // round-nearest-even
  uint32_t u = __float_as_uint(f);
  uint32_t r = (u + 0x7fffu + ((u >> 16) & 1u)) >> 16;
  return (short)r;
}
__device__ __forceinline__ float bf2f(short s) {
  return __uint_as_float(((uint32_t)(uint16_t)s) << 16);
}
// packed 2xf32 -> 2xbf16 (hardware op when available)
__device__ __forceinline__ uint32_t f2bf_pk(float a, float b) {
#if __has_builtin(__builtin_amdgcn_cvt_pk_bf16_f32)
  auto r = __builtin_amdgcn_cvt_pk_bf16_f32(a, b);
  uint32_t u; __builtin_memcpy(&u, &r, sizeof(u));
  return u;
#else
  uint32_t ua = (__float_as_uint(a) + 0x8000u) >> 16;
  uint32_t ub = (__float_as_uint(b) + 0x8000u) >> 16;
  return ua | (ub << 16);
#endif
}
// raw v_exp_f32 (2^x)
__device__ __forceinline__ float fast_exp2(float x) {
#if __has_builtin(__builtin_amdgcn_exp2f)
  return __builtin_amdgcn_exp2f(x);
#else
  return exp2f(x);
#endif
}

__device__ __forceinline__ void gload_lds16(const void* g, void* l) {
  __builtin_amdgcn_global_load_lds((const __attribute__((address_space(1))) void*)g,
                                   (__attribute__((address_space(3))) void*)l, 16, 0, 0);
}

// ---------------- fused fp32 -> bf16 convert for all 5 tensors ------------------
struct Cvt5Args {
  const float *s0, *s1, *s2, *s3, *s4;
  short *d0, *d1, *d2, *d3, *d4;
};
#define CV0 2097152             // hs      (float4 units)
#define CV1 (CV0 + 1048576)     // Wq
#define CV2 (CV1 + 262144)      // Wk
#define CV3 (CV2 + 262144)      // Wv
#define CV4 (CV3 + 1048576)     // Wo -> total 4718592
__global__ void cvt5_kernel(Cvt5Args a) {
  int i = blockIdx.x * blockDim.x + threadIdx.x;
  const float* s; short* d; int off;
  if      (i < CV0) { s = a.s0; d = a.d0; off = i; }
  else if (i < CV1) { s = a.s1; d = a.d1; off = i - CV0; }
  else if (i < CV2) { s = a.s2; d = a.d2; off = i - CV1; }
  else if (i < CV3) { s = a.s3; d = a.d3; off = i - CV2; }
  else              { s = a.s4; d = a.d4; off = i - CV3; }
  const float4 v = ((const float4*)s)[off];
  uint2 o;
  o.x = (uint32_t)(uint16_t)f2bf(v.x) | ((uint32_t)(uint16_t)f2bf(v.y) << 16);
  o.y = (uint32_t)(uint16_t)f2bf(v.z) | ((uint32_t)(uint16_t)f2bf(v.w) << 16);
  ((uint2*)d)[off] = o;
}

// ---------------- 128x192 QKV-cat GEMM: grid 16x32 = 512 blocks = 2/CU ---------
// Ccat[4096,3072] = X[4096,2048] * Wcat[3072,2048]^T. BK=64, 512 threads =
// 8 waves (2M x 4N); per wave 64x48 output = 4x3 16x16 frags (48 acc VGPR).
// LDS = A 2x16K + B 2x24K = EXACTLY 80 KiB -> 2 blocks/CU (4 waves/SIMD).
// R7-verified: 52 us, MfmaUtil ~41, 990 TF. Cross-block overlap (m114) covers
// the end-of-tile vmcnt(0) drain. Protocol & XOR swizzle unchanged.
__global__ __launch_bounds__(512, 4) void gemm_qkvcat(
    const short* __restrict__ A, const short* __restrict__ Bcat,
    short* __restrict__ Ccat)
{
  __shared__ __align__(16) short As[2][128 * 64];   // 32 KiB
  __shared__ __align__(16) short Bs[2][192 * 64];   // 48 KiB

  const long tileM = (long)blockIdx.y * 128;
  const long tileN = (long)blockIdx.x * 192;
  const int  K = 2048;

  const int tid  = threadIdx.x;
  const int lane = tid & 63;
  const int quad = lane >> 4;
  const int l15  = lane & 15;
  const int wave = tid >> 6;
  const int wm   = (wave >> 2) * 64;      // 0 / 64
  const int wn   = (wave & 3) * 48;       // 0..144 (multiple of 16)
  const int xsw  = l15 & 7;

  f32x4 acc[4][3];
#pragma unroll
  for (int i = 0; i < 4; ++i)
#pragma unroll
    for (int j = 0; j < 3; ++j) acc[i][j] = f32x4{0.f, 0.f, 0.f, 0.f};

  // Staging: thread c = tid + 512p covers row c>>3, LDS chunk c&7 (linear dest).
  // Global source chunk = swizzle inverse. A: 2 passes (128 rows), B: 3 (192).
  const int cS = (tid & 7) ^ ((tid >> 3) & 7);
  const short* gA[2]; const short* gB[3];
#pragma unroll
  for (int p = 0; p < 2; ++p)
    gA[p] = A + (tileM + (tid >> 3) + 64 * p) * K + cS * 8;
#pragma unroll
  for (int p = 0; p < 3; ++p)
    gB[p] = Bcat + (tileN + (tid >> 3) + 64 * p) * K + cS * 8;

  auto stage = [&](int buf, int t) {
    const long ko = (long)t * 64;
    short* la = &As[buf][0];
    short* lb = &Bs[buf][0];
#pragma unroll
    for (int p = 0; p < 2; ++p)
      gload_lds16(gA[p] + ko, la + (tid + p * 512) * 8);
#pragma unroll
    for (int p = 0; p < 3; ++p)
      gload_lds16(gB[p] + ko, lb + (tid + p * 512) * 8);
  };

  const int NT = K / 64;                       // 32
  stage(0, 0);
  asm volatile("s_waitcnt vmcnt(0)" ::: "memory");
  asm volatile("s_barrier" ::: "memory");

  bf16x8 af[2][2], bfr[3][2];

  auto ldA = [&](const short* Ab, int half) {
#pragma unroll
    for (int m = 0; m < 2; ++m) {
      const int r = wm + (half * 2 + m) * 16 + l15;
#pragma unroll
      for (int kk = 0; kk < 2; ++kk)
        af[m][kk] = *(const bf16x8*)&Ab[r * 64 + (((kk * 4 + quad) ^ xsw) << 3)];
    }
  };
  auto ldB = [&](const short* Bb) {
#pragma unroll
    for (int n = 0; n < 3; ++n) {
      const int r = wn + n * 16 + l15;
#pragma unroll
      for (int kk = 0; kk < 2; ++kk)
        bfr[n][kk] = *(const bf16x8*)&Bb[r * 64 + (((kk * 4 + quad) ^ xsw) << 3)];
    }
  };
  auto mma = [&](int half) {
    __builtin_amdgcn_s_setprio(1);
#pragma unroll
    for (int m = 0; m < 2; ++m)
#pragma unroll
      for (int n = 0; n < 3; ++n)
#pragma unroll
        for (int kk = 0; kk < 2; ++kk)
          acc[half * 2 + m][n] = MFMA16(af[m][kk], bfr[n][kk], acc[half * 2 + m][n]);
    __builtin_amdgcn_s_setprio(0);
  };

  for (int t = 0; t < NT; ++t) {
    const int cur = t & 1;
    const short* Ab = &As[cur][0];
    const short* Bb = &Bs[cur][0];

    // phase 0: stage next tile, mf-half 0 (B loaded once, reused in half 1)
    if (t + 1 < NT) stage(cur ^ 1, t + 1);
    ldB(Bb); ldA(Ab, 0); mma(0);
    asm volatile("s_barrier" ::: "memory");
    // phase 1: mf-half 1
    ldA(Ab, 1); mma(1);
    asm volatile("s_waitcnt vmcnt(0)" ::: "memory");    // next-tile DMA landed
    asm volatile("s_waitcnt lgkmcnt(0)" ::: "memory");  // my reads of slot cur done
    asm volatile("s_barrier" ::: "memory");             // release slot cur
  }

#pragma unroll
  for (int i = 0; i < 4; ++i)
#pragma unroll
    for (int j = 0; j < 3; ++j)
#pragma unroll
      for (int r = 0; r < 4; ++r) {
        long row = tileM + wm + i * 16 + quad * 4 + r;
        long col = tileN + wn + j * 16 + l15;
        Ccat[row * CSTR + col] = f2bf(acc[i][j][r]);
      }
}

// ---------------- 128x128 GEMM (output projection): 512 blocks = 2/CU ----------
// Cf[4096,2048] = A[4096,2048] * Wo[2048,2048]^T, fp32 epilogue. Same protocol.
// Per wave 64x32 = 4x2 frags (32 acc VGPR). LDS 64 KiB -> 2 blocks/CU.
__global__ __launch_bounds__(512, 4) void gemm_out(
    const short* __restrict__ A, const short* __restrict__ Bm,
    float* __restrict__ Cf)
{
  __shared__ __align__(16) short As[2][128 * 64];   // 32 KiB
  __shared__ __align__(16) short Bs[2][128 * 64];   // 32 KiB

  const int N = 2048, K = 2048;
  const long tileM = (long)blockIdx.y * 128;
  const long tileN = (long)blockIdx.x * 128;

  const int tid  = threadIdx.x;
  const int lane = tid & 63;
  const int quad = lane >> 4;
  const int l15  = lane & 15;
  const int wave = tid >> 6;
  const int wm   = (wave >> 2) * 64;
  const int wn   = (wave & 3) * 32;
  const int xsw  = l15 & 7;

  f32x4 acc[4][2];
#pragma unroll
  for (int i = 0; i < 4; ++i)
#pragma unroll
    for (int j = 0; j < 2; ++j) acc[i][j] = f32x4{0.f, 0.f, 0.f, 0.f};

  const int cS = (tid & 7) ^ ((tid >> 3) & 7);
  const short* gA[2]; const short* gB[2];
#pragma unroll
  for (int p = 0; p < 2; ++p) {
    gA[p] = A  + (tileM + (tid >> 3) + 64 * p) * K + cS * 8;
    gB[p] = Bm + (tileN + (tid >> 3) + 64 * p) * K + cS * 8;
  }

  auto stage = [&](int buf, int t) {
    const long ko = (long)t * 64;
    short* la = &As[buf][0];
    short* lb = &Bs[buf][0];
#pragma unroll
    for (int p = 0; p < 2; ++p) {
      gload_lds16(gA[p] + ko, la + (tid + p * 512) * 8);
      gload_lds16(gB[p] + ko, lb + (tid + p * 512) * 8);
    }
  };

  const int NT = K / 64;
  stage(0, 0);
  asm volatile("s_waitcnt vmcnt(0)" ::: "memory");
  asm volatile("s_barrier" ::: "memory");

  bf16x8 af[2][2], bfr[2][2];

  auto ldA = [&](const short* Ab, int half) {
#pragma unroll
    for (int m = 0; m < 2; ++m) {
      const int r = wm + (half * 2 + m) * 16 + l15;
#pragma unroll
      for (int kk = 0; kk < 2; ++kk)
        af[m][kk] = *(const bf16x8*)&Ab[r * 64 + (((kk * 4 + quad) ^ xsw) << 3)];
    }
  };
  auto ldB = [&](const short* Bb) {
#pragma unroll
    for (int n = 0; n < 2; ++n) {
      const int r = wn + n * 16 + l15;
#pragma unroll
      for (int kk = 0; kk < 2; ++kk)
        bfr[n][kk] = *(const bf16x8*)&Bb[r * 64 + (((kk * 4 + quad) ^ xsw) << 3)];
    }
  };
  auto mma = [&](int half) {
    __builtin_amdgcn_s_setprio(1);
#pragma unroll
    for (int m = 0; m < 2; ++m)
#pragma unroll
      for (int n = 0; n < 2; ++n)
#pragma unroll
        for (int kk = 0; kk < 2; ++kk)
          acc[half * 2 + m][n] = MFMA16(af[m][kk], bfr[n][kk], acc[half * 2 + m][n]);
    __builtin_amdgcn_s_setprio(0);
  };

  for (int t = 0; t < NT; ++t) {
    const int cur = t & 1;
    const short* Ab = &As[cur][0];
    const short* Bb = &Bs[cur][0];

    if (t + 1 < NT) stage(cur ^ 1, t + 1);
    ldB(Bb); ldA(Ab, 0); mma(0);
    asm volatile("s_barrier" ::: "memory");
    ldA(Ab, 1); mma(1);
    asm volatile("s_waitcnt vmcnt(0)" ::: "memory");
    asm volatile("s_waitcnt lgkmcnt(0)" ::: "memory");
    asm volatile("s_barrier" ::: "memory");
  }

#pragma unroll
  for (int i = 0; i < 4; ++i)
#pragma unroll
    for (int j = 0; j < 2; ++j)
#pragma unroll
      for (int r = 0; r < 4; ++r) {
        long row = tileM + wm + i * 16 + quad * 4 + r;
        long col = tileN + wn + j * 16 + l15;
        Cf[row * N + col] = acc[i][j][r];
      }
}

// ---------------- fused RoPE (Q,K in-place in Ccat) + V transpose ---------------
// Q = Ccat cols 0..2047, K = cols 2048..2559, V = cols 2560..3071 (stride 3072).
// Vectorized x8; math identical to previous (bit-identical output).
// Q scaled by (1/8)*log2(e); V^T written slot-permuted for the attn PV A-frag.
#define ROPE_BLOCKS 2560          // Q: 2048 blocks, K: 512 blocks (x8 vectorized)
__global__ void rope_vtrans_kernel(short* __restrict__ Ccat, short* __restrict__ Vt) {
  __shared__ short tile[64][65];
  if (blockIdx.x < ROPE_BLOCKS) {
    const int QT = (B_ * S_) * NH_ * 4;  // 524288 Q threads (4 groups of 8 per head)
    int t = blockIdx.x * blockDim.x + threadIdx.x;
    long base; int g; float scale; int row;
    if (t < QT) {
      row = t >> 7; int rem = t & 127, head = rem >> 2; g = rem & 3;
      base = (long)row * CSTR + head * HD_;
      scale = 0.125f * 1.44269504f;
    } else {
      int t2 = t - QT;
      row = t2 >> 5; int rem = t2 & 31, head = rem >> 2; g = rem & 3;
      base = (long)row * CSTR + 2048 + head * HD_;
      scale = 1.0f;
    }
    const int s = row & (S_ - 1);
    const int i0 = g * 8;
    union V8 { bf16x8 v; short e[8]; };
    V8 x0, x1, y0, y1;
    x0.v = *(const bf16x8*)&Ccat[base + i0];
    x1.v = *(const bf16x8*)&Ccat[base + i0 + 32];
#pragma unroll
    for (int j = 0; j < 8; ++j) {
      const int i = i0 + j;
      float invr = exp2f((float)i * -0.41524101f) * 0.15915494309f;
      float rev = (float)s * invr;
      rev -= floorf(rev);
      float ar = rev * 6.28318530718f;
      float c = __cosf(ar), sn = __sinf(ar);
      float a = bf2f(x0.e[j]);
      float b = bf2f(x1.e[j]);
      y0.e[j] = f2bf((a * c - b * sn) * scale);
      y1.e[j] = f2bf((b * c + a * sn) * scale);
    }
    *(bf16x8*)&Ccat[base + i0]      = y0.v;
    *(bf16x8*)&Ccat[base + i0 + 32] = y1.v;
  } else {
    int blk = blockIdx.x - ROPE_BLOCKS;
    int s0 = (blk & 31) * 64;
    int h  = (blk >> 5) & 7;
    int b  = blk >> 8;
    int tid = threadIdx.x;
#pragma unroll
    for (int it = 0; it < 16; ++it) {
      int idx = tid + it * 256;
      int r = idx >> 6, c = idx & 63;
      tile[r][c] = Ccat[((long)(b * S_ + s0 + r)) * CSTR + 2560 + h * HD_ + c];
    }
    __syncthreads();
#pragma unroll
    for (int it = 0; it < 16; ++it) {
      int idx = tid + it * 256;
      int d = idx >> 6, s = idx & 63;
      int slot = (s & 0x20) | (((s >> 2) & 3) << 3) | (((s >> 4) & 1) << 2) | (s & 3);
      Vt[((long)((b * NKV_ + h) * HD_ + d)) * S_ + s0 + slot] = tile[s][d];
    }
  }
}

// ---------------- Flash attention (causal, GQA), transposed-score form ----------
// Grid (16, 64) = 1024 blocks with the R10-verified XCD-aware remap (each
// (b,hkv) K/V column pinned to one XCD; FETCH 33.8 -> 12.4 MB, K/V L2-hot).
// 2 LDS buffers (32 KiB), 1-deep prefetch, 2-slot protocol verbatim from the
// verified gemm_qkvcat. R11 POST-MORTEM: __launch_bounds__(256,5) squeezed
// VGPR to 48 -> massive spill (WRITE_SIZE 16->165 MB, MfmaUtil 8%). Fixed:
// bounds (256,3) -- the allocation R10 compiled to 84 VGPR spill-free.
// Residency = min(LDS 160/32 = 5 blocks/CU, VGPR 512/84 = 6 waves/SIMD)
// = 5 blocks/CU (20 waves) WITHOUT the allocator squeeze.
// 128 q-rows per block (two 16-row fragments per wave).
__global__ __launch_bounds__(256, 3) void attn_kernel(
    const short* __restrict__ Ccat, const short* __restrict__ Vt,
    short* __restrict__ O)
{
  // ---- XCD-aware index derivation (pure remap of the linear block id) ----
  const int l    = (int)blockIdx.x + 16 * (int)blockIdx.y;  // 0..1023
  const int r8   = l & 7;                 // XCD residue (round-robin)
  const int m    = l >> 3;                // 0..127
  const int kvcol = r8 + 8 * (m >> 6);    // 0..15 = b*8 + hkv (2 per XCD)
  const int idx  = m & 63;                // 0..63 within column
  const int qt   = 15 - (idx & 15);       // long q-tiles dispatch first
  const int kmax = 2 * qt + 1;            // last 64-key tile index
  const int b    = kvcol >> 3;
  const int hkv  = kvcol & 7;
  const int h    = hkv * 4 + (idx >> 4);  // head within the GQA group

  const int tid = threadIdx.x, lane = tid & 63, w = tid >> 6;
  const int quad = lane >> 4, l15 = lane & 15;

  __shared__ __align__(16) short Ks[2][64 * 64];   // [key][feature], chunk-swizzled
  __shared__ __align__(16) short Vs[2][64 * 64];   // [d][slot], chunk-swizzled

  const int qbase = qt * 128 + w * 16;   // frag0 rows qbase+l15, frag1 +64
  const short* qb0 = Ccat + ((long)(b * S_ + qbase + l15)) * CSTR + h * HD_;
  const short* qb1 = qb0 + 64L * CSTR;
  const bf16x8 aq00 = *(const bf16x8*)(qb0 + quad * 8);
  const bf16x8 aq01 = *(const bf16x8*)(qb0 + 32 + quad * 8);
  const bf16x8 aq10 = *(const bf16x8*)(qb1 + quad * 8);
  const bf16x8 aq11 = *(const bf16x8*)(qb1 + 32 + quad * 8);

  f32x4 o0[4], o1[4];
#pragma unroll
  for (int i = 0; i < 4; ++i) {
    o0[i] = f32x4{0.f, 0.f, 0.f, 0.f};
    o1[i] = f32x4{0.f, 0.f, 0.f, 0.f};
  }
  f32x4 li0 = f32x4{0.f, 0.f, 0.f, 0.f};
  f32x4 li1 = f32x4{0.f, 0.f, 0.f, 0.f};

  const short* kg = Ccat + ((long)(b * S_)) * CSTR + 2048 + hkv * HD_;
  const short* vg = Vt + ((long)((b * NKV_ + hkv) * HD_)) * S_;

  const int rK = tid >> 3;                       // 0..31 (second half adds 32)
  const int cC = (tid & 7) ^ (rK & 7);           // +32 preserves &7
  const short* kSrc = kg + (long)rK * CSTR + cC * 8;
  const short* vSrc = vg + (long)rK * S_ + cC * 8;
  short* kDst = &Ks[0][tid * 8];
  short* vDst = &Vs[0][tid * 8];

  auto stage = [&](int buf, int kb) {
    const long ko = (long)kb * 64 * CSTR;
    const long vo = (long)kb * 64;
    const int bo = buf * 4096;
    gload_lds16(kSrc + ko,              kDst + bo);
    gload_lds16(kSrc + ko + 32L * CSTR, kDst + bo + 2048);
    gload_lds16(vSrc + vo,              vDst + bo);
    gload_lds16(vSrc + vo + 32L * S_,   vDst + bo + 2048);
  };

  // prologue: stage tile 0, collective-ready via own-vmcnt + barrier
  stage(0, 0);
  asm volatile("s_waitcnt vmcnt(0)" ::: "memory");
  asm volatile("s_barrier" ::: "memory");

  const int thr = w * 16 + l15;   // diagonal mask threshold (key offset vs row)
  union U8 { uint32_t u[4]; bf16x8 v; };

  int cur = 0;
  for (int kb = 0; kb <= kmax; ++kb) {
    // 1-deep prefetch into the other slot (slot safe: its readers finished at
    // the end-of-previous-iteration lgkmcnt(0)+barrier)
    if (kb < kmax) stage(cur ^ 1, kb + 1);
    const short* Kb = &Ks[cur][0];
    const short* Vb = &Vs[cur][0];
    const bool doF0 = (kb != kmax);              // frag0 fully masked at kmax

    // ---- Sc^T = K·Q^T (K-frags shared across both q-fragments) ----
    f32x4 s0[4], s1[4];
    __builtin_amdgcn_s_setprio(1);
#pragma unroll
    for (int nt = 0; nt < 4; ++nt) {
      const int r = nt * 16 + l15;
      bf16x8 k0 = *(const bf16x8*)&Kb[(r * 8 + ((quad)     ^ (r & 7))) * 8];
      bf16x8 k1 = *(const bf16x8*)&Kb[(r * 8 + ((quad + 4) ^ (r & 7))) * 8];
      f32x4 t = f32x4{0.f, 0.f, 0.f, 0.f};
      t = MFMA16(k0, aq10, t);
      t = MFMA16(k1, aq11, t);
      s1[nt] = t;
      if (doF0) {
        f32x4 u = f32x4{0.f, 0.f, 0.f, 0.f};
        u = MFMA16(k0, aq00, u);
        u = MFMA16(k1, aq01, u);
        s0[nt] = u;
      }
    }
    __builtin_amdgcn_s_setprio(0);

    // ---- causal mask (diagonal tiles only) ----
    if (kb == kmax) {            // frag1 diagonal
#pragma unroll
      for (int nt = 0; nt < 4; ++nt) {
        const int base = nt * 16 + quad * 4;
#pragma unroll
        for (int rr = 0; rr < 4; ++rr)
          if (base + rr > thr) s1[nt][rr] = -1e30f;
      }
    }
    if (doF0 && kb == kmax - 1) {   // frag0 diagonal
#pragma unroll
      for (int nt = 0; nt < 4; ++nt) {
        const int base = nt * 16 + quad * 4;
#pragma unroll
        for (int rr = 0; rr < 4; ++rr)
          if (base + rr > thr) s0[nt][rr] = -1e30f;
      }
    }

    // ---- exp2 + pack to P^T B-fragments (registers only) ----
    U8 p0[2], p1[2];
#pragma unroll
    for (int kt = 0; kt < 2; ++kt) {
      float e0 = fast_exp2(s1[2 * kt][0]),     e1 = fast_exp2(s1[2 * kt][1]);
      float e2 = fast_exp2(s1[2 * kt][2]),     e3 = fast_exp2(s1[2 * kt][3]);
      float e4 = fast_exp2(s1[2 * kt + 1][0]), e5 = fast_exp2(s1[2 * kt + 1][1]);
      float e6 = fast_exp2(s1[2 * kt + 1][2]), e7 = fast_exp2(s1[2 * kt + 1][3]);
      p1[kt].u[0] = f2bf_pk(e0, e1);
      p1[kt].u[1] = f2bf_pk(e2, e3);
      p1[kt].u[2] = f2bf_pk(e4, e5);
      p1[kt].u[3] = f2bf_pk(e6, e7);
      li1 += f32x4{e0, e1, e2, e3};
      li1 += f32x4{e4, e5, e6, e7};
    }
    if (doF0) {
#pragma unroll
      for (int kt = 0; kt < 2; ++kt) {
        float e0 = fast_exp2(s0[2 * kt][0]),     e1 = fast_exp2(s0[2 * kt][1]);
        float e2 = fast_exp2(s0[2 * kt][2]),     e3 = fast_exp2(s0[2 * kt][3]);
        float e4 = fast_exp2(s0[2 * kt + 1][0]), e5 = fast_exp2(s0[2 * kt + 1][1]);
        float e6 = fast_exp2(s0[2 * kt + 1][2]), e7 = fast_exp2(s0[2 * kt + 1][3]);
        p0[kt].u[0] = f2bf_pk(e0, e1);
        p0[kt].u[1] = f2bf_pk(e2, e3);
        p0[kt].u[2] = f2bf_pk(e4, e5);
        p0[kt].u[3] = f2bf_pk(e6, e7);
        li0 += f32x4{e0, e1, e2, e3};
        li0 += f32x4{e4, e5, e6, e7};
      }
    }

    // ---- O^T += V^T · P^T (V A-frags shared across both q-fragments) ----
    __builtin_amdgcn_s_setprio(1);
#pragma unroll
    for (int kt = 0; kt < 2; ++kt) {
      bf16x8 vf[4];
#pragma unroll
      for (int dt = 0; dt < 4; ++dt)
        vf[dt] = *(const bf16x8*)&Vb[(dt * 16 + l15) * 64 +
                                     (((kt * 4 + quad) ^ (l15 & 7)) << 3)];
#pragma unroll
      for (int dt = 0; dt < 4; ++dt)
        o1[dt] = MFMA16(vf[dt], p1[kt].v, o1[dt]);
      if (doF0) {
#pragma unroll
        for (int dt = 0; dt < 4; ++dt)
          o0[dt] = MFMA16(vf[dt], p0[kt].v, o0[dt]);
      }
    }
    __builtin_amdgcn_s_setprio(0);

    // end-of-iteration: next-tile DMA landed (overlapped with the compute
    // above), my LDS reads of slot cur serviced, then collective release.
    asm volatile("s_waitcnt vmcnt(0)" ::: "memory");
    asm volatile("s_waitcnt lgkmcnt(0)" ::: "memory");
    asm volatile("s_barrier" ::: "memory");
    cur ^= 1;
  }

  // ---- epilogue: O^T C-layout -> lane holds qrow=l15, d = dt*16+quad*4+r ----
  auto epi = [&](f32x4 (&o)[4], const f32x4& li4, int qrow0) {
    float l2 = (li4[0] + li4[1]) + (li4[2] + li4[3]);
    l2 += __shfl_xor(l2, 16, 64);
    l2 += __shfl_xor(l2, 32, 64);
    float invl = 1.0f / l2;
    long orow = (long)(b * S_ + qrow0 + l15);
#pragma unroll
    for (int dt = 0; dt < 4; ++dt) {
      uint2 st;
      st.x = f2bf_pk(o[dt][0] * invl, o[dt][1] * invl);
      st.y = f2bf_pk(o[dt][2] * invl, o[dt][3] * invl);
      *(uint2*)&O[orow * (NH_ * HD_) + h * HD_ + dt * 16 + quad * 4] = st;
    }
  };
  epi(o1, li1, qbase + 64);
  epi(o0, li0, qbase);
}

// ---------------- launch -------------------------------------------------------
extern "C" void kernel_launch(void* const* d_in, const int* in_sizes, int n_in,
                              void* d_out, int out_size, void* d_ws, size_t ws_size,
                              hipStream_t stream) {
  const float* hs = (const float*)d_in[0];
  const float* Wq = (const float*)d_in[1];
  const float* Wk = (const float*)d_in[2];
  const float* Wv = (const float*)d_in[3];
  const float* Wo = (const float*)d_in[4];
  float* out = (float*)d_out;

  char* p = (char*)d_ws;
  auto carve = [&](size_t elems) { short* r = (short*)p; p += elems * 2; return r; };
  short* Xb   = carve(8388608);    // hidden bf16 [4096,2048]
  short* Wcat = carve(6291456);    // [Wq;Wk;Wv] rows -> [3072,2048]
  short* Wob  = carve(4194304);
  short* Ccat = carve(12582912);   // QKV-cat [4096,3072]
  short* Vtt  = carve(2097152);    // V^T [B,KV,HD,S] (slot-permuted)
  short* Om   = carve(8388608);    // attn out [4096,2048]

  short* Wqb = Wcat;               // rows 0..2047
  short* Wkb = Wcat + 4194304;     // rows 2048..2559
  short* Wvb = Wcat + 5242880;     // rows 2560..3071

  Cvt5Args ca{hs, Wq, Wk, Wv, Wo, Xb, Wqb, Wkb, Wvb, Wob};
  cvt5_kernel<<<CV4 / 256, 256, 0, stream>>>(ca);

  // QKV-cat projection: 128x192 tiles, grid 16x32 = 512 blocks = 2/CU
  gemm_qkvcat<<<dim3(16, 32), 512, 0, stream>>>(Xb, Wcat, Ccat);

  rope_vtrans_kernel<<<ROPE_BLOCKS + 512, 256, 0, stream>>>(Ccat, Vtt);

  // attention: single launch, grid (16,64) = 1024 blocks, XCD-aware remap,
  // 2-slot LDS (32 KiB), bounds (256,3) -> 5 blocks/CU resident, no spill
  attn_kernel<<<dim3(16, 64, 1), 256, 0, stream>>>(Ccat, Vtt, Om);

  // Output projection: 128x128 tiles, grid 16x32 = 512 blocks = 2/CU
  gemm_out<<<dim3(16, 32), 512, 0, stream>>>(Om, Wob, out);
}

// Round 13
// 259.526 us; speedup vs baseline: 1.4312x; 1.0747x over previous
//
#include <hip/hip_runtime.h>
#include <hip/hip_bf16.h>
#include <cstdint>
#include <cmath>

// Problem constants
#define B_   2
#define S_   2048
#define H_   2048
#define NH_  32
#define NKV_ 8
#define HD_  64
#define CSTR 3072   // row stride of the concatenated QKV output [4096, 3072]

using bf16x8 = __attribute__((ext_vector_type(8))) short;
using f32x4  = __attribute__((ext_vector_type(4))) float;

#define MFMA16(a, b, c) __builtin_amdgcn_mfma_f32_16x16x32_bf16((a), (b), (c), 0, 0, 0)

__device__ __forceinline__ short f2bf(float f) {   // round-nearest-even
  uint32_t u = __float_as_uint(f);
  uint32_t r = (u + 0x7fffu + ((u >> 16) & 1u)) >> 16;
  return (short)r;
}
__device__ __forceinline__ float bf2f(short s) {
  return __uint_as_float(((uint32_t)(uint16_t)s) << 16);
}
// packed 2xf32 -> 2xbf16 (hardware op when available)
__device__ __forceinline__ uint32_t f2bf_pk(float a, float b) {
#if __has_builtin(__builtin_amdgcn_cvt_pk_bf16_f32)
  auto r = __builtin_amdgcn_cvt_pk_bf16_f32(a, b);
  uint32_t u; __builtin_memcpy(&u, &r, sizeof(u));
  return u;
#else
  uint32_t ua = (__float_as_uint(a) + 0x8000u) >> 16;
  uint32_t ub = (__float_as_uint(b) + 0x8000u) >> 16;
  return ua | (ub << 16);
#endif
}
// raw v_exp_f32 (2^x)
__device__ __forceinline__ float fast_exp2(float x) {
#if __has_builtin(__builtin_amdgcn_exp2f)
  return __builtin_amdgcn_exp2f(x);
#else
  return exp2f(x);
#endif
}

__device__ __forceinline__ void gload_lds16(const void* g, void* l) {
  __builtin_amdgcn_global_load_lds((const __attribute__((address_space(1))) void*)g,
                                   (__attribute__((address_space(3))) void*)l, 16, 0, 0);
}

// ---------------- fused fp32 -> bf16 convert for all 5 tensors ------------------
struct Cvt5Args {
  const float *s0, *s1, *s2, *s3, *s4;
  short *d0, *d1, *d2, *d3, *d4;
};
#define CV0 2097152             // hs      (float4 units)
#define CV1 (CV0 + 1048576)     // Wq
#define CV2 (CV1 + 262144)      // Wk
#define CV3 (CV2 + 262144)      // Wv
#define CV4 (CV3 + 1048576)     // Wo -> total 4718592
__global__ void cvt5_kernel(Cvt5Args a) {
  int i = blockIdx.x * blockDim.x + threadIdx.x;
  const float* s; short* d; int off;
  if      (i < CV0) { s = a.s0; d = a.d0; off = i; }
  else if (i < CV1) { s = a.s1; d = a.d1; off = i - CV0; }
  else if (i < CV2) { s = a.s2; d = a.d2; off = i - CV1; }
  else if (i < CV3) { s = a.s3; d = a.d3; off = i - CV2; }
  else              { s = a.s4; d = a.d4; off = i - CV3; }
  const float4 v = ((const float4*)s)[off];
  uint2 o;
  o.x = (uint32_t)(uint16_t)f2bf(v.x) | ((uint32_t)(uint16_t)f2bf(v.y) << 16);
  o.y = (uint32_t)(uint16_t)f2bf(v.z) | ((uint32_t)(uint16_t)f2bf(v.w) << 16);
  ((uint2*)d)[off] = o;
}

// ---------------- 128x192 QKV-cat GEMM: grid 16x32 = 512 blocks = 2/CU ---------
// Ccat[4096,3072] = X[4096,2048] * Wcat[3072,2048]^T. BK=64, 512 threads =
// 8 waves (2M x 4N); per wave 64x48 output = 4x3 16x16 frags (48 acc VGPR).
// LDS = A 2x16K + B 2x24K = EXACTLY 80 KiB -> 2 blocks/CU (4 waves/SIMD).
// R7-verified: 52 us, MfmaUtil ~41, 990 TF. Cross-block overlap (m114) covers
// the end-of-tile vmcnt(0) drain. Protocol & XOR swizzle unchanged.
__global__ __launch_bounds__(512, 4) void gemm_qkvcat(
    const short* __restrict__ A, const short* __restrict__ Bcat,
    short* __restrict__ Ccat)
{
  __shared__ __align__(16) short As[2][128 * 64];   // 32 KiB
  __shared__ __align__(16) short Bs[2][192 * 64];   // 48 KiB

  const long tileM = (long)blockIdx.y * 128;
  const long tileN = (long)blockIdx.x * 192;
  const int  K = 2048;

  const int tid  = threadIdx.x;
  const int lane = tid & 63;
  const int quad = lane >> 4;
  const int l15  = lane & 15;
  const int wave = tid >> 6;
  const int wm   = (wave >> 2) * 64;      // 0 / 64
  const int wn   = (wave & 3) * 48;       // 0..144 (multiple of 16)
  const int xsw  = l15 & 7;

  f32x4 acc[4][3];
#pragma unroll
  for (int i = 0; i < 4; ++i)
#pragma unroll
    for (int j = 0; j < 3; ++j) acc[i][j] = f32x4{0.f, 0.f, 0.f, 0.f};

  // Staging: thread c = tid + 512p covers row c>>3, LDS chunk c&7 (linear dest).
  // Global source chunk = swizzle inverse. A: 2 passes (128 rows), B: 3 (192).
  const int cS = (tid & 7) ^ ((tid >> 3) & 7);
  const short* gA[2]; const short* gB[3];
#pragma unroll
  for (int p = 0; p < 2; ++p)
    gA[p] = A + (tileM + (tid >> 3) + 64 * p) * K + cS * 8;
#pragma unroll
  for (int p = 0; p < 3; ++p)
    gB[p] = Bcat + (tileN + (tid >> 3) + 64 * p) * K + cS * 8;

  auto stage = [&](int buf, int t) {
    const long ko = (long)t * 64;
    short* la = &As[buf][0];
    short* lb = &Bs[buf][0];
#pragma unroll
    for (int p = 0; p < 2; ++p)
      gload_lds16(gA[p] + ko, la + (tid + p * 512) * 8);
#pragma unroll
    for (int p = 0; p < 3; ++p)
      gload_lds16(gB[p] + ko, lb + (tid + p * 512) * 8);
  };

  const int NT = K / 64;                       // 32
  stage(0, 0);
  asm volatile("s_waitcnt vmcnt(0)" ::: "memory");
  asm volatile("s_barrier" ::: "memory");

  bf16x8 af[2][2], bfr[3][2];

  auto ldA = [&](const short* Ab, int half) {
#pragma unroll
    for (int m = 0; m < 2; ++m) {
      const int r = wm + (half * 2 + m) * 16 + l15;
#pragma unroll
      for (int kk = 0; kk < 2; ++kk)
        af[m][kk] = *(const bf16x8*)&Ab[r * 64 + (((kk * 4 + quad) ^ xsw) << 3)];
    }
  };
  auto ldB = [&](const short* Bb) {
#pragma unroll
    for (int n = 0; n < 3; ++n) {
      const int r = wn + n * 16 + l15;
#pragma unroll
      for (int kk = 0; kk < 2; ++kk)
        bfr[n][kk] = *(const bf16x8*)&Bb[r * 64 + (((kk * 4 + quad) ^ xsw) << 3)];
    }
  };
  auto mma = [&](int half) {
    __builtin_amdgcn_s_setprio(1);
#pragma unroll
    for (int m = 0; m < 2; ++m)
#pragma unroll
      for (int n = 0; n < 3; ++n)
#pragma unroll
        for (int kk = 0; kk < 2; ++kk)
          acc[half * 2 + m][n] = MFMA16(af[m][kk], bfr[n][kk], acc[half * 2 + m][n]);
    __builtin_amdgcn_s_setprio(0);
  };

  for (int t = 0; t < NT; ++t) {
    const int cur = t & 1;
    const short* Ab = &As[cur][0];
    const short* Bb = &Bs[cur][0];

    // phase 0: stage next tile, mf-half 0 (B loaded once, reused in half 1)
    if (t + 1 < NT) stage(cur ^ 1, t + 1);
    ldB(Bb); ldA(Ab, 0); mma(0);
    asm volatile("s_barrier" ::: "memory");
    // phase 1: mf-half 1
    ldA(Ab, 1); mma(1);
    asm volatile("s_waitcnt vmcnt(0)" ::: "memory");    // next-tile DMA landed
    asm volatile("s_waitcnt lgkmcnt(0)" ::: "memory");  // my reads of slot cur done
    asm volatile("s_barrier" ::: "memory");             // release slot cur
  }

#pragma unroll
  for (int i = 0; i < 4; ++i)
#pragma unroll
    for (int j = 0; j < 3; ++j)
#pragma unroll
      for (int r = 0; r < 4; ++r) {
        long row = tileM + wm + i * 16 + quad * 4 + r;
        long col = tileN + wn + j * 16 + l15;
        Ccat[row * CSTR + col] = f2bf(acc[i][j][r]);
      }
}

// ---------------- 128x128 GEMM (output projection): 512 blocks = 2/CU ----------
// Cf[4096,2048] = A[4096,2048] * Wo[2048,2048]^T, fp32 epilogue. Same protocol.
// Per wave 64x32 = 4x2 frags (32 acc VGPR). LDS 64 KiB -> 2 blocks/CU.
__global__ __launch_bounds__(512, 4) void gemm_out(
    const short* __restrict__ A, const short* __restrict__ Bm,
    float* __restrict__ Cf)
{
  __shared__ __align__(16) short As[2][128 * 64];   // 32 KiB
  __shared__ __align__(16) short Bs[2][128 * 64];   // 32 KiB

  const int N = 2048, K = 2048;
  const long tileM = (long)blockIdx.y * 128;
  const long tileN = (long)blockIdx.x * 128;

  const int tid  = threadIdx.x;
  const int lane = tid & 63;
  const int quad = lane >> 4;
  const int l15  = lane & 15;
  const int wave = tid >> 6;
  const int wm   = (wave >> 2) * 64;
  const int wn   = (wave & 3) * 32;
  const int xsw  = l15 & 7;

  f32x4 acc[4][2];
#pragma unroll
  for (int i = 0; i < 4; ++i)
#pragma unroll
    for (int j = 0; j < 2; ++j) acc[i][j] = f32x4{0.f, 0.f, 0.f, 0.f};

  const int cS = (tid & 7) ^ ((tid >> 3) & 7);
  const short* gA[2]; const short* gB[2];
#pragma unroll
  for (int p = 0; p < 2; ++p) {
    gA[p] = A  + (tileM + (tid >> 3) + 64 * p) * K + cS * 8;
    gB[p] = Bm + (tileN + (tid >> 3) + 64 * p) * K + cS * 8;
  }

  auto stage = [&](int buf, int t) {
    const long ko = (long)t * 64;
    short* la = &As[buf][0];
    short* lb = &Bs[buf][0];
#pragma unroll
    for (int p = 0; p < 2; ++p) {
      gload_lds16(gA[p] + ko, la + (tid + p * 512) * 8);
      gload_lds16(gB[p] + ko, lb + (tid + p * 512) * 8);
    }
  };

  const int NT = K / 64;
  stage(0, 0);
  asm volatile("s_waitcnt vmcnt(0)" ::: "memory");
  asm volatile("s_barrier" ::: "memory");

  bf16x8 af[2][2], bfr[2][2];

  auto ldA = [&](const short* Ab, int half) {
#pragma unroll
    for (int m = 0; m < 2; ++m) {
      const int r = wm + (half * 2 + m) * 16 + l15;
#pragma unroll
      for (int kk = 0; kk < 2; ++kk)
        af[m][kk] = *(const bf16x8*)&Ab[r * 64 + (((kk * 4 + quad) ^ xsw) << 3)];
    }
  };
  auto ldB = [&](const short* Bb) {
#pragma unroll
    for (int n = 0; n < 2; ++n) {
      const int r = wn + n * 16 + l15;
#pragma unroll
      for (int kk = 0; kk < 2; ++kk)
        bfr[n][kk] = *(const bf16x8*)&Bb[r * 64 + (((kk * 4 + quad) ^ xsw) << 3)];
    }
  };
  auto mma = [&](int half) {
    __builtin_amdgcn_s_setprio(1);
#pragma unroll
    for (int m = 0; m < 2; ++m)
#pragma unroll
      for (int n = 0; n < 2; ++n)
#pragma unroll
        for (int kk = 0; kk < 2; ++kk)
          acc[half * 2 + m][n] = MFMA16(af[m][kk], bfr[n][kk], acc[half * 2 + m][n]);
    __builtin_amdgcn_s_setprio(0);
  };

  for (int t = 0; t < NT; ++t) {
    const int cur = t & 1;
    const short* Ab = &As[cur][0];
    const short* Bb = &Bs[cur][0];

    if (t + 1 < NT) stage(cur ^ 1, t + 1);
    ldB(Bb); ldA(Ab, 0); mma(0);
    asm volatile("s_barrier" ::: "memory");
    ldA(Ab, 1); mma(1);
    asm volatile("s_waitcnt vmcnt(0)" ::: "memory");
    asm volatile("s_waitcnt lgkmcnt(0)" ::: "memory");
    asm volatile("s_barrier" ::: "memory");
  }

#pragma unroll
  for (int i = 0; i < 4; ++i)
#pragma unroll
    for (int j = 0; j < 2; ++j)
#pragma unroll
      for (int r = 0; r < 4; ++r) {
        long row = tileM + wm + i * 16 + quad * 4 + r;
        long col = tileN + wn + j * 16 + l15;
        Cf[row * N + col] = acc[i][j][r];
      }
}

// ---------------- fused RoPE (Q,K in-place in Ccat) + V transpose ---------------
// Q = Ccat cols 0..2047, K = cols 2048..2559, V = cols 2560..3071 (stride 3072).
// Vectorized x8; math identical to previous (bit-identical output).
// Q scaled by (1/8)*log2(e); V^T written slot-permuted for the attn PV A-frag.
#define ROPE_BLOCKS 2560          // Q: 2048 blocks, K: 512 blocks (x8 vectorized)
__global__ void rope_vtrans_kernel(short* __restrict__ Ccat, short* __restrict__ Vt) {
  __shared__ short tile[64][65];
  if (blockIdx.x < ROPE_BLOCKS) {
    const int QT = (B_ * S_) * NH_ * 4;  // 524288 Q threads (4 groups of 8 per head)
    int t = blockIdx.x * blockDim.x + threadIdx.x;
    long base; int g; float scale; int row;
    if (t < QT) {
      row = t >> 7; int rem = t & 127, head = rem >> 2; g = rem & 3;
      base = (long)row * CSTR + head * HD_;
      scale = 0.125f * 1.44269504f;
    } else {
      int t2 = t - QT;
      row = t2 >> 5; int rem = t2 & 31, head = rem >> 2; g = rem & 3;
      base = (long)row * CSTR + 2048 + head * HD_;
      scale = 1.0f;
    }
    const int s = row & (S_ - 1);
    const int i0 = g * 8;
    union V8 { bf16x8 v; short e[8]; };
    V8 x0, x1, y0, y1;
    x0.v = *(const bf16x8*)&Ccat[base + i0];
    x1.v = *(const bf16x8*)&Ccat[base + i0 + 32];
#pragma unroll
    for (int j = 0; j < 8; ++j) {
      const int i = i0 + j;
      float invr = exp2f((float)i * -0.41524101f) * 0.15915494309f;
      float rev = (float)s * invr;
      rev -= floorf(rev);
      float ar = rev * 6.28318530718f;
      float c = __cosf(ar), sn = __sinf(ar);
      float a = bf2f(x0.e[j]);
      float b = bf2f(x1.e[j]);
      y0.e[j] = f2bf((a * c - b * sn) * scale);
      y1.e[j] = f2bf((b * c + a * sn) * scale);
    }
    *(bf16x8*)&Ccat[base + i0]      = y0.v;
    *(bf16x8*)&Ccat[base + i0 + 32] = y1.v;
  } else {
    int blk = blockIdx.x - ROPE_BLOCKS;
    int s0 = (blk & 31) * 64;
    int h  = (blk >> 5) & 7;
    int b  = blk >> 8;
    int tid = threadIdx.x;
#pragma unroll
    for (int it = 0; it < 16; ++it) {
      int idx = tid + it * 256;
      int r = idx >> 6, c = idx & 63;
      tile[r][c] = Ccat[((long)(b * S_ + s0 + r)) * CSTR + 2560 + h * HD_ + c];
    }
    __syncthreads();
#pragma unroll
    for (int it = 0; it < 16; ++it) {
      int idx = tid + it * 256;
      int d = idx >> 6, s = idx & 63;
      int slot = (s & 0x20) | (((s >> 2) & 3) << 3) | (((s >> 4) & 1) << 2) | (s & 3);
      Vt[((long)((b * NKV_ + h) * HD_ + d)) * S_ + s0 + slot] = tile[s][d];
    }
  }
}

// ---------------- Flash attention (causal, GQA), transposed-score form ----------
// WORK-BALANCED PAIRING (R12 post-mortem): the (16,64)=1024-block grid had a
// 2..32-iteration length spread with only 4 blocks/CU total -> the kernel tail
// was one qt=15 block per column running alone (measured occupancy ~16%).
// Now each block processes TWO q-tiles SEQUENTIALLY, paired (qt, 15-qt):
// (2qt+2)+(2(15-qt)+2) = 34 iterations for EVERY block. Grid (8,64) = 512
// blocks = 2/CU, all identical length -> zero tail, steady residency; the two
// co-resident blocks cover each other's drains (m114). Register pressure
// unchanged (tiles processed one after the other, state reset between).
// XCD-aware remap retained: per XCD, 64 blocks covering the same 2 (b,hkv)
// K/V columns -> K/V stays L2-hot (R10: FETCH 33.8 -> 12.4 MB).
// Per-row math and tile order identical to R12 -> bit-identical output.
// 2 LDS buffers (32 KiB), 1-deep prefetch, 2-slot protocol (R12-verified).
__global__ __launch_bounds__(256, 3) void attn_kernel(
    const short* __restrict__ Ccat, const short* __restrict__ Vt,
    short* __restrict__ O)
{
  // ---- XCD-aware index derivation (pure remap of the linear block id) ----
  const int l    = (int)blockIdx.x + 8 * (int)blockIdx.y;   // 0..511
  const int r8   = l & 7;                 // XCD residue (round-robin)
  const int m    = l >> 3;                // 0..63
  const int kvcol = r8 + 8 * (m >> 5);    // 0..15 = b*8 + hkv (2 per XCD)
  const int idx  = m & 31;                // 0..31 within column
  const int b    = kvcol >> 3;
  const int hkv  = kvcol & 7;
  const int h    = hkv * 4 + (idx >> 3);  // head within the GQA group
  const int pair = idx & 7;               // q-tile pair id: tiles {15-pair, pair}

  const int tid = threadIdx.x, lane = tid & 63, w = tid >> 6;
  const int quad = lane >> 4, l15 = lane & 15;

  __shared__ __align__(16) short Ks[2][64 * 64];   // [key][feature], chunk-swizzled
  __shared__ __align__(16) short Vs[2][64 * 64];   // [d][slot], chunk-swizzled

  const short* kg = Ccat + ((long)(b * S_)) * CSTR + 2048 + hkv * HD_;
  const short* vg = Vt + ((long)((b * NKV_ + hkv) * HD_)) * S_;

  const int rK = tid >> 3;                       // 0..31 (second half adds 32)
  const int cC = (tid & 7) ^ (rK & 7);           // +32 preserves &7
  const short* kSrc = kg + (long)rK * CSTR + cC * 8;
  const short* vSrc = vg + (long)rK * S_ + cC * 8;
  short* kDst = &Ks[0][tid * 8];
  short* vDst = &Vs[0][tid * 8];

  auto stage = [&](int buf, int kb) {
    const long ko = (long)kb * 64 * CSTR;
    const long vo = (long)kb * 64;
    const int bo = buf * 4096;
    gload_lds16(kSrc + ko,              kDst + bo);
    gload_lds16(kSrc + ko + 32L * CSTR, kDst + bo + 2048);
    gload_lds16(vSrc + vo,              vDst + bo);
    gload_lds16(vSrc + vo + 32L * S_,   vDst + bo + 2048);
  };

  const int thr = w * 16 + l15;   // diagonal mask threshold (key offset vs row)
  union U8 { uint32_t u[4]; bf16x8 v; };

  auto run_tile = [&](int qt) {
    const int kmax = 2 * qt + 1;           // last 64-key tile index
    const int qbase = qt * 128 + w * 16;   // frag0 rows qbase+l15, frag1 +64
    const short* qb0 = Ccat + ((long)(b * S_ + qbase + l15)) * CSTR + h * HD_;
    const short* qb1 = qb0 + 64L * CSTR;
    const bf16x8 aq00 = *(const bf16x8*)(qb0 + quad * 8);
    const bf16x8 aq01 = *(const bf16x8*)(qb0 + 32 + quad * 8);
    const bf16x8 aq10 = *(const bf16x8*)(qb1 + quad * 8);
    const bf16x8 aq11 = *(const bf16x8*)(qb1 + 32 + quad * 8);

    f32x4 o0[4], o1[4];
#pragma unroll
    for (int i = 0; i < 4; ++i) {
      o0[i] = f32x4{0.f, 0.f, 0.f, 0.f};
      o1[i] = f32x4{0.f, 0.f, 0.f, 0.f};
    }
    f32x4 li0 = f32x4{0.f, 0.f, 0.f, 0.f};
    f32x4 li1 = f32x4{0.f, 0.f, 0.f, 0.f};

    // prologue: stage tile 0 (previous pass fully drained at its last barrier)
    stage(0, 0);
    asm volatile("s_waitcnt vmcnt(0)" ::: "memory");
    asm volatile("s_barrier" ::: "memory");

    int cur = 0;
    for (int kb = 0; kb <= kmax; ++kb) {
      // 1-deep prefetch into the other slot (readers finished at the end of
      // the previous iteration's lgkmcnt(0)+barrier)
      if (kb < kmax) stage(cur ^ 1, kb + 1);
      const short* Kb = &Ks[cur][0];
      const short* Vb = &Vs[cur][0];
      const bool doF0 = (kb != kmax);            // frag0 fully masked at kmax

      // ---- Sc^T = K·Q^T (K-frags shared across both q-fragments) ----
      f32x4 s0[4], s1[4];
      __builtin_amdgcn_s_setprio(1);
#pragma unroll
      for (int nt = 0; nt < 4; ++nt) {
        const int r = nt * 16 + l15;
        bf16x8 k0 = *(const bf16x8*)&Kb[(r * 8 + ((quad)     ^ (r & 7))) * 8];
        bf16x8 k1 = *(const bf16x8*)&Kb[(r * 8 + ((quad + 4) ^ (r & 7))) * 8];
        f32x4 t = f32x4{0.f, 0.f, 0.f, 0.f};
        t = MFMA16(k0, aq10, t);
        t = MFMA16(k1, aq11, t);
        s1[nt] = t;
        if (doF0) {
          f32x4 u = f32x4{0.f, 0.f, 0.f, 0.f};
          u = MFMA16(k0, aq00, u);
          u = MFMA16(k1, aq01, u);
          s0[nt] = u;
        }
      }
      __builtin_amdgcn_s_setprio(0);

      // ---- causal mask (diagonal tiles only) ----
      if (kb == kmax) {            // frag1 diagonal
#pragma unroll
        for (int nt = 0; nt < 4; ++nt) {
          const int base = nt * 16 + quad * 4;
#pragma unroll
          for (int rr = 0; rr < 4; ++rr)
            if (base + rr > thr) s1[nt][rr] = -1e30f;
        }
      }
      if (doF0 && kb == kmax - 1) {   // frag0 diagonal
#pragma unroll
        for (int nt = 0; nt < 4; ++nt) {
          const int base = nt * 16 + quad * 4;
#pragma unroll
          for (int rr = 0; rr < 4; ++rr)
            if (base + rr > thr) s0[nt][rr] = -1e30f;
        }
      }

      // ---- exp2 + pack to P^T B-fragments (registers only) ----
      U8 p0[2], p1[2];
#pragma unroll
      for (int kt = 0; kt < 2; ++kt) {
        float e0 = fast_exp2(s1[2 * kt][0]),     e1 = fast_exp2(s1[2 * kt][1]);
        float e2 = fast_exp2(s1[2 * kt][2]),     e3 = fast_exp2(s1[2 * kt][3]);
        float e4 = fast_exp2(s1[2 * kt + 1][0]), e5 = fast_exp2(s1[2 * kt + 1][1]);
        float e6 = fast_exp2(s1[2 * kt + 1][2]), e7 = fast_exp2(s1[2 * kt + 1][3]);
        p1[kt].u[0] = f2bf_pk(e0, e1);
        p1[kt].u[1] = f2bf_pk(e2, e3);
        p1[kt].u[2] = f2bf_pk(e4, e5);
        p1[kt].u[3] = f2bf_pk(e6, e7);
        li1 += f32x4{e0, e1, e2, e3};
        li1 += f32x4{e4, e5, e6, e7};
      }
      if (doF0) {
#pragma unroll
        for (int kt = 0; kt < 2; ++kt) {
          float e0 = fast_exp2(s0[2 * kt][0]),     e1 = fast_exp2(s0[2 * kt][1]);
          float e2 = fast_exp2(s0[2 * kt][2]),     e3 = fast_exp2(s0[2 * kt][3]);
          float e4 = fast_exp2(s0[2 * kt + 1][0]), e5 = fast_exp2(s0[2 * kt + 1][1]);
          float e6 = fast_exp2(s0[2 * kt + 1][2]), e7 = fast_exp2(s0[2 * kt + 1][3]);
          p0[kt].u[0] = f2bf_pk(e0, e1);
          p0[kt].u[1] = f2bf_pk(e2, e3);
          p0[kt].u[2] = f2bf_pk(e4, e5);
          p0[kt].u[3] = f2bf_pk(e6, e7);
          li0 += f32x4{e0, e1, e2, e3};
          li0 += f32x4{e4, e5, e6, e7};
        }
      }

      // ---- O^T += V^T · P^T (V A-frags shared across both q-fragments) ----
      __builtin_amdgcn_s_setprio(1);
#pragma unroll
      for (int kt = 0; kt < 2; ++kt) {
        bf16x8 vf[4];
#pragma unroll
        for (int dt = 0; dt < 4; ++dt)
          vf[dt] = *(const bf16x8*)&Vb[(dt * 16 + l15) * 64 +
                                       (((kt * 4 + quad) ^ (l15 & 7)) << 3)];
#pragma unroll
        for (int dt = 0; dt < 4; ++dt)
          o1[dt] = MFMA16(vf[dt], p1[kt].v, o1[dt]);
        if (doF0) {
#pragma unroll
          for (int dt = 0; dt < 4; ++dt)
            o0[dt] = MFMA16(vf[dt], p0[kt].v, o0[dt]);
        }
      }
      __builtin_amdgcn_s_setprio(0);

      // end-of-iteration: next-tile DMA landed (overlapped with the compute
      // above), my LDS reads of slot cur serviced, then collective release.
      asm volatile("s_waitcnt vmcnt(0)" ::: "memory");
      asm volatile("s_waitcnt lgkmcnt(0)" ::: "memory");
      asm volatile("s_barrier" ::: "memory");
      cur ^= 1;
    }

    // ---- epilogue: O^T C-layout -> lane holds qrow=l15, d = dt*16+quad*4+r --
    auto epi = [&](f32x4 (&o)[4], const f32x4& li4, int qrow0) {
      float l2 = (li4[0] + li4[1]) + (li4[2] + li4[3]);
      l2 += __shfl_xor(l2, 16, 64);
      l2 += __shfl_xor(l2, 32, 64);
      float invl = 1.0f / l2;
      long orow = (long)(b * S_ + qrow0 + l15);
#pragma unroll
      for (int dt = 0; dt < 4; ++dt) {
        uint2 st;
        st.x = f2bf_pk(o[dt][0] * invl, o[dt][1] * invl);
        st.y = f2bf_pk(o[dt][2] * invl, o[dt][3] * invl);
        *(uint2*)&O[orow * (NH_ * HD_) + h * HD_ + dt * 16 + quad * 4] = st;
      }
    };
    epi(o1, li1, qbase + 64);
    epi(o0, li0, qbase);
  };

  run_tile(15 - pair);   // long tile first
  run_tile(pair);        // short tile second -> every block = 34 iterations
}

// ---------------- launch -------------------------------------------------------
extern "C" void kernel_launch(void* const* d_in, const int* in_sizes, int n_in,
                              void* d_out, int out_size, void* d_ws, size_t ws_size,
                              hipStream_t stream) {
  const float* hs = (const float*)d_in[0];
  const float* Wq = (const float*)d_in[1];
  const float* Wk = (const float*)d_in[2];
  const float* Wv = (const float*)d_in[3];
  const float* Wo = (const float*)d_in[4];
  float* out = (float*)d_out;

  char* p = (char*)d_ws;
  auto carve = [&](size_t elems) { short* r = (short*)p; p += elems * 2; return r; };
  short* Xb   = carve(8388608);    // hidden bf16 [4096,2048]
  short* Wcat = carve(6291456);    // [Wq;Wk;Wv] rows -> [3072,2048]
  short* Wob  = carve(4194304);
  short* Ccat = carve(12582912);   // QKV-cat [4096,3072]
  short* Vtt  = carve(2097152);    // V^T [B,KV,HD,S] (slot-permuted)
  short* Om   = carve(8388608);    // attn out [4096,2048]

  short* Wqb = Wcat;               // rows 0..2047
  short* Wkb = Wcat + 4194304;     // rows 2048..2559
  short* Wvb = Wcat + 5242880;     // rows 2560..3071

  Cvt5Args ca{hs, Wq, Wk, Wv, Wo, Xb, Wqb, Wkb, Wvb, Wob};
  cvt5_kernel<<<CV4 / 256, 256, 0, stream>>>(ca);

  // QKV-cat projection: 128x192 tiles, grid 16x32 = 512 blocks = 2/CU
  gemm_qkvcat<<<dim3(16, 32), 512, 0, stream>>>(Xb, Wcat, Ccat);

  rope_vtrans_kernel<<<ROPE_BLOCKS + 512, 256, 0, stream>>>(Ccat, Vtt);

  // attention: grid (8,64) = 512 blocks = 2/CU, every block exactly 34
  // iterations (paired q-tiles), XCD-aware remap, 2-slot LDS (32 KiB)
  attn_kernel<<<dim3(8, 64, 1), 256, 0, stream>>>(Ccat, Vtt, Om);

  // Output projection: 128x128 tiles, grid 16x32 = 512 blocks = 2/CU
  gemm_out<<<dim3(16, 32), 512, 0, stream>>>(Om, Wob, out);
}